// Round 3
// baseline (825.169 us; speedup 1.0000x reference)
//
#include <hip/hip_runtime.h>
#include <cstdint>

typedef __attribute__((ext_vector_type(8))) short short8;
typedef __attribute__((ext_vector_type(4))) float f32x4;

#define DEVINL static __device__ __forceinline__

DEVINL ushort f2b(float f) {
    uint32_t u = __builtin_bit_cast(uint32_t, f);
    u += 0x7FFFu + ((u >> 16) & 1u);
    return (ushort)(u >> 16);
}

// ---------------------------------------------------------------------------
// Generic bf16 MFMA GEMM:  C[M,N] = A[M,K] @ BT[N,K]^T (+bias) with epilogues.
// mfma_f32_16x16x32_bf16 layouts:
//   A: lane holds A[m=lane&15][k=(lane>>4)*8+j]   (16B contiguous)
//   B: lane holds B[k=(lane>>4)*8+j][n=lane&15] -> BT[n][k..k+8) contiguous
//   C/D: lane,reg r -> row=(lane>>4)*4+r, col=lane&15
// ---------------------------------------------------------------------------
constexpr int EPI_F32      = 0;  // outf = acc + bias
constexpr int EPI_F32_BF16 = 1;  // outf and outb
constexpr int EPI_MUL_BF16 = 2;  // outb = (acc+bias) * extra[row*N+col]
constexpr int EPI_SCALE_FB = 3;  // v = (acc+bias)*extra[row]; outf & outb
constexpr int EPI_WH       = 4;  // outf+outb AND atomic row-dots vs asrc/adst

template<int K, int EPI>
__global__ __launch_bounds__(256) void gemm_k(
    const ushort* __restrict__ A, const ushort* __restrict__ BT,
    const float* __restrict__ bias, int N,
    float* __restrict__ outf, ushort* __restrict__ outb, int obld, int oboff,
    const float* __restrict__ extra,
    const float* __restrict__ asrc, const float* __restrict__ adst,
    float* __restrict__ sOut, float* __restrict__ dOut)
{
    const int wave = threadIdx.x >> 6;
    const int lane = threadIdx.x & 63;
    const int quad = lane >> 4;
    const int l16  = lane & 15;
    const int m0 = blockIdx.x * 64;
    const int n0 = blockIdx.y * 64;
    const int arow = m0 + wave * 16 + l16;
    const ushort* Ap = A + (size_t)arow * K;

    f32x4 zero = {0.f, 0.f, 0.f, 0.f};
    f32x4 acc[4] = {zero, zero, zero, zero};

    #pragma unroll
    for (int k0 = 0; k0 < K; k0 += 32) {
        const int kk = k0 + quad * 8;
        short8 af = *(const short8*)(Ap + kk);
        #pragma unroll
        for (int c = 0; c < 4; ++c) {
            const ushort* Bp = BT + (size_t)(n0 + c * 16 + l16) * K + kk;
            short8 bf = *(const short8*)Bp;
            acc[c] = __builtin_amdgcn_mfma_f32_16x16x32_bf16(af, bf, acc[c], 0, 0, 0);
        }
    }

    const int orow0 = m0 + wave * 16 + quad * 4;
    #pragma unroll
    for (int r = 0; r < 4; ++r) {
        const int row = orow0 + r;
        float sp = 0.f, dp = 0.f;
        #pragma unroll
        for (int c = 0; c < 4; ++c) {
            const int col = n0 + c * 16 + l16;
            float v = acc[c][r] + (bias ? bias[col] : 0.f);
            if (EPI == EPI_MUL_BF16) v *= extra[(size_t)row * N + col];
            if (EPI == EPI_SCALE_FB) v *= extra[row];
            if (EPI == EPI_F32 || EPI == EPI_F32_BF16 || EPI == EPI_SCALE_FB || EPI == EPI_WH)
                outf[(size_t)row * N + col] = v;
            if (EPI == EPI_F32_BF16 || EPI == EPI_MUL_BF16 || EPI == EPI_SCALE_FB || EPI == EPI_WH)
                outb[(size_t)row * obld + oboff + col] = f2b(v);
            if (EPI == EPI_WH) { sp += v * asrc[col]; dp += v * adst[col]; }
        }
        if (EPI == EPI_WH) {
            #pragma unroll
            for (int o = 1; o < 16; o <<= 1) {
                sp += __shfl_xor(sp, o);
                dp += __shfl_xor(dp, o);
            }
            if (l16 == 0) {
                atomicAdd(&sOut[row], sp);
                atomicAdd(&dOut[row], dp);
            }
        }
    }
}

// ---------------------------------------------------------------------------
// Fused GAT attention, round 3: BARRIER-FREE streaming loop, zero LDS.
// Each wave computes its own P (A-operand) fragments in registers and loads
// B fragments (16B) directly from L2-resident WhT. i-tile 64 (dual A-frags,
// 2x B reuse), 8 col-tiles/wave. Grid (128, 4 js): 512 blocks = 2/CU.
// Partials: Upart[js][i][256] f32, lpart[js][i]; combine kernel divides.
// ---------------------------------------------------------------------------
__global__ __launch_bounds__(256) void attn_kernel(
    const int* __restrict__ adj, const float* __restrict__ sA,
    const float* __restrict__ dA, const ushort* __restrict__ WhT,
    float* __restrict__ Upart, float* __restrict__ lpart)
{
    const int tid  = threadIdx.x;
    const int wave = tid >> 6, lane = tid & 63, quad = lane >> 4, l16 = lane & 15;
    const int i0 = blockIdx.x * 64;
    const int js = blockIdx.y;
    const int jbase = js * 2048;
    const int rt = wave & 1, ch = wave >> 1;     // row half / col half
    const int rowbase = i0 + rt * 32;
    const int r0 = rowbase + l16, r1 = rowbase + 16 + l16;
    const float s0 = sA[r0], s1 = sA[r1];
    const int*   adj0 = adj + (size_t)r0 * 8192 + jbase + quad * 8;
    const int*   adj1 = adj + (size_t)r1 * 8192 + jbase + quad * 8;
    const float* dAp  = dA + jbase + quad * 8;
    const ushort* Bb  = WhT + (size_t)(ch * 128 + l16) * 8192 + jbase + quad * 8;

    f32x4 zero = {0.f, 0.f, 0.f, 0.f};
    f32x4 accA[8] = {zero, zero, zero, zero, zero, zero, zero, zero};
    f32x4 accB[8] = {zero, zero, zero, zero, zero, zero, zero, zero};
    float ls0 = 0.f, ls1 = 0.f;

    #pragma unroll 2
    for (int j = 0; j < 2048; j += 32) {
        const int4   a0a = *(const int4*)  (adj0 + j);
        const int4   a0b = *(const int4*)  (adj0 + j + 4);
        const int4   a1a = *(const int4*)  (adj1 + j);
        const int4   a1b = *(const int4*)  (adj1 + j + 4);
        const float4 d0  = *(const float4*)(dAp + j);
        const float4 d1  = *(const float4*)(dAp + j + 4);
        const float dd[8]  = {d0.x, d0.y, d0.z, d0.w, d1.x, d1.y, d1.z, d1.w};
        const int   aa0[8] = {a0a.x, a0a.y, a0a.z, a0a.w, a0b.x, a0b.y, a0b.z, a0b.w};
        const int   aa1[8] = {a1a.x, a1a.y, a1a.z, a1a.w, a1b.x, a1b.y, a1b.z, a1b.w};
        union { ushort us[8]; short8 v; } p0, p1;
        #pragma unroll
        for (int q = 0; q < 8; ++q) {
            float e0 = s0 + dd[q];
            e0 = fmaxf(e0, 0.2f * e0);                 // leaky_relu(0.2)
            const float w0 = aa0[q] ? __expf(e0) : 0.f;
            ls0 += w0; p0.us[q] = f2b(w0);
            float e1 = s1 + dd[q];
            e1 = fmaxf(e1, 0.2f * e1);
            const float w1 = aa1[q] ? __expf(e1) : 0.f;
            ls1 += w1; p1.us[q] = f2b(w1);
        }
        #pragma unroll
        for (int c = 0; c < 8; ++c) {
            short8 bf = *(const short8*)(Bb + (size_t)c * 16 * 8192 + j);
            accA[c] = __builtin_amdgcn_mfma_f32_16x16x32_bf16(p0.v, bf, accA[c], 0, 0, 0);
            accB[c] = __builtin_amdgcn_mfma_f32_16x16x32_bf16(p1.v, bf, accB[c], 0, 0, 0);
        }
    }

    // row sums: partials live per (l16=row, quad); fold quads (stride 16)
    ls0 += __shfl_down(ls0, 32); ls0 += __shfl_down(ls0, 16);
    ls1 += __shfl_down(ls1, 32); ls1 += __shfl_down(ls1, 16);
    if (ch == 0 && lane < 16) {
        lpart[(size_t)js * 8192 + rowbase + lane]      = ls0;
        lpart[(size_t)js * 8192 + rowbase + 16 + lane] = ls1;
    }

    #pragma unroll
    for (int c = 0; c < 8; ++c) {
        const int col = ch * 128 + c * 16 + l16;
        #pragma unroll
        for (int r = 0; r < 4; ++r) {
            Upart[((size_t)js * 8192 + rowbase + quad * 4 + r) * 256 + col]      = accA[c][r];
            Upart[((size_t)js * 8192 + rowbase + 16 + quad * 4 + r) * 256 + col] = accB[c][r];
        }
    }
}

// combine: h_attn = (sum_js U) / (sum_js l); write f32 + comb[:,0:256] bf16
__global__ __launch_bounds__(256) void attn_combine_kernel(
    const float* __restrict__ Upart, const float* __restrict__ lpart,
    float* __restrict__ outf, ushort* __restrict__ outb)
{
    const int row = blockIdx.x * 4 + (threadIdx.x >> 6);
    const int lane = threadIdx.x & 63;
    float l = 0.f;
    #pragma unroll
    for (int js = 0; js < 4; ++js) l += lpart[(size_t)js * 8192 + row];
    const float inv = 1.f / l;
    #pragma unroll
    for (int i = 0; i < 4; ++i) {
        const int c = i * 64 + lane;
        float u = 0.f;
        #pragma unroll
        for (int js = 0; js < 4; ++js)
            u += Upart[((size_t)js * 8192 + row) * 256 + c];
        const float v = u * inv;
        outf[(size_t)row * 256 + c] = v;
        outb[(size_t)row * 512 + c] = f2b(v);
    }
}

// ---------------------------------------------------------------------------
// Descriptor-driven transpose/cast mega-kernel: all weight transposes + the
// h cast in ONE dispatch (was 11). R>0: f32[R][C] -> bf16[C][R] (32x32 tiles,
// t = tile index, bx = t % (C/32), by = t / (C/32)). R==0: flat cast of C
// elements, 1024 per block.
// ---------------------------------------------------------------------------
struct TJob { const float* in; ushort* out; int R, C, off; };
struct TArgs { TJob j[10]; };

__global__ __launch_bounds__(256) void multi_transpose_kernel(TArgs a)
{
    __shared__ float tile[32][33];
    const int b = blockIdx.x;
    int ji = 0;
    #pragma unroll
    for (int k = 1; k < 10; ++k) if (b >= a.j[k].off) ji = k;
    const TJob J = a.j[ji];
    const int t = b - J.off;

    if (J.R == 0) {            // flat cast
        const int base = t * 1024 + threadIdx.x;
        #pragma unroll
        for (int k = 0; k < 4; ++k)
            J.out[base + k * 256] = f2b(J.in[base + k * 256]);
        return;
    }
    const int CB = J.C >> 5;
    const int bx = t % CB, by = t / CB;
    const int tx = threadIdx.x & 31, ty = threadIdx.x >> 5;
    const int c0 = bx * 32, r0 = by * 32;
    #pragma unroll
    for (int i = ty; i < 32; i += 8)
        tile[i][tx] = J.in[(size_t)(r0 + i) * J.C + (c0 + tx)];
    __syncthreads();
    #pragma unroll
    for (int i = ty; i < 32; i += 8)
        J.out[(size_t)(c0 + i) * J.R + (r0 + tx)] = f2b(tile[tx][i]);
}

// f32 [R][C] -> bf16 [C][R]  (still used for Wh -> WhT, mid-pipeline)
__global__ __launch_bounds__(256) void transpose_cast_kernel(
    const float* __restrict__ in, ushort* __restrict__ out, int R, int C)
{
    __shared__ float tile[32][33];
    const int tx = threadIdx.x & 31, ty = threadIdx.x >> 5;
    const int c0 = blockIdx.x * 32, r0 = blockIdx.y * 32;
    #pragma unroll
    for (int i = ty; i < 32; i += 8)
        tile[i][tx] = in[(size_t)(r0 + i) * C + (c0 + tx)];
    __syncthreads();
    #pragma unroll
    for (int i = ty; i < 32; i += 8)
        out[(size_t)(c0 + i) * R + (r0 + tx)] = f2b(tile[tx][i]);
}

// LayerNorm(512) + silu -> bf16 (wave per row)
__global__ __launch_bounds__(256) void ln_silu_512_kernel(
    const float* __restrict__ in, const float* __restrict__ g,
    const float* __restrict__ b, ushort* __restrict__ outb)
{
    const int row = blockIdx.x * 4 + (threadIdx.x >> 6);
    const int lane = threadIdx.x & 63;
    const size_t base = (size_t)row * 512;
    float x[8]; float sum = 0.f, sq = 0.f;
    #pragma unroll
    for (int i = 0; i < 8; ++i) {
        const float v = in[base + i * 64 + lane];
        x[i] = v; sum += v; sq += v * v;
    }
    #pragma unroll
    for (int o = 32; o; o >>= 1) { sum += __shfl_xor(sum, o); sq += __shfl_xor(sq, o); }
    const float mean = sum * (1.f / 512.f);
    const float var  = sq * (1.f / 512.f) - mean * mean;
    const float rstd = rsqrtf(var + 1e-5f);
    #pragma unroll
    for (int i = 0; i < 8; ++i) {
        const int c = i * 64 + lane;
        const float y = (x[i] - mean) * rstd * g[c] + b[c];
        outb[base + c] = f2b(y / (1.f + __expf(-y)));   // silu
    }
}

// SSM front: softmax(dt+A)*B -> SB bf16; cscale = 1 + C@cp_w + cp_b
__global__ __launch_bounds__(256) void ssm_front_kernel(
    const float* __restrict__ BCdt, const float* __restrict__ Avec,
    const float* __restrict__ cpw, const float* __restrict__ cpb,
    ushort* __restrict__ SB, float* __restrict__ cscale)
{
    const int row = blockIdx.x * 4 + (threadIdx.x >> 6);
    const int lane = threadIdx.x & 63;
    const float* rp = BCdt + (size_t)row * 384;
    const float B0 = rp[lane],       B1 = rp[64 + lane];
    const float C0 = rp[128 + lane], C1 = rp[192 + lane];
    float t0 = rp[256 + lane] + Avec[lane];
    float t1 = rp[320 + lane] + Avec[64 + lane];
    float mx = fmaxf(t0, t1);
    #pragma unroll
    for (int o = 32; o; o >>= 1) mx = fmaxf(mx, __shfl_xor(mx, o));
    const float e0 = __expf(t0 - mx), e1 = __expf(t1 - mx);
    float ssum = e0 + e1;
    #pragma unroll
    for (int o = 32; o; o >>= 1) ssum += __shfl_xor(ssum, o);
    const float inv = 1.f / ssum;
    SB[(size_t)row * 128 + lane]      = f2b(e0 * inv * B0);
    SB[(size_t)row * 128 + 64 + lane] = f2b(e1 * inv * B1);
    float cp = C0 * cpw[lane] + C1 * cpw[64 + lane];
    #pragma unroll
    for (int o = 32; o; o >>= 1) cp += __shfl_xor(cp, o);
    if (lane == 0) cscale[row] = 1.f + cp + cpb[0];
}

// v = h_part * (silu(z) + D) from hz[8192,1024] -> bf16 [8192,512]
__global__ void hz_act_kernel(const float* __restrict__ hz,
                              const float* __restrict__ Dp, ushort* __restrict__ out)
{
    const float D0 = Dp[0];
    const int n = 8192 * 512;
    for (int i = blockIdx.x * blockDim.x + threadIdx.x; i < n; i += gridDim.x * blockDim.x) {
        const int r = i >> 9, c = i & 511;
        const float hp = hz[(size_t)r * 1024 + c];
        const float z  = hz[(size_t)r * 1024 + 512 + c];
        out[i] = f2b(hp * (z / (1.f + __expf(-z)) + D0));
    }
}

// g = sigmoid(gl); fused = g*ha + (1-g)*hs2 + he; LayerNorm(256) -> out f32
__global__ __launch_bounds__(256) void final_kernel(
    const float* __restrict__ gl, const float* __restrict__ ha,
    const float* __restrict__ hs2, const float* __restrict__ he,
    const float* __restrict__ lng, const float* __restrict__ lnb,
    float* __restrict__ outp)
{
    const int row = blockIdx.x * 4 + (threadIdx.x >> 6);
    const int lane = threadIdx.x & 63;
    const size_t base = (size_t)row * 256;
    float f[4]; float sum = 0.f, sq = 0.f;
    #pragma unroll
    for (int i = 0; i < 4; ++i) {
        const int c = i * 64 + lane;
        const float gv = 1.f / (1.f + __expf(-gl[base + c]));
        const float v = gv * ha[base + c] + (1.f - gv) * hs2[base + c] + he[base + c];
        f[i] = v; sum += v; sq += v * v;
    }
    #pragma unroll
    for (int o = 32; o; o >>= 1) { sum += __shfl_xor(sum, o); sq += __shfl_xor(sq, o); }
    const float mean = sum * (1.f / 256.f);
    const float var  = sq * (1.f / 256.f) - mean * mean;
    const float rstd = rsqrtf(var + 1e-5f);
    #pragma unroll
    for (int i = 0; i < 4; ++i) {
        const int c = i * 64 + lane;
        outp[base + c] = (f[i] - mean) * rstd * lng[c] + lnb[c];
    }
}

// ---------------------------------------------------------------------------
extern "C" void kernel_launch(void* const* d_in, const int* in_sizes, int n_in,
                              void* d_out, int out_size, void* d_ws, size_t ws_size,
                              hipStream_t stream)
{
    const float* h      = (const float*)d_in[0];
    const int*   adj    = (const int*)  d_in[1];
    const float* W      = (const float*)d_in[2];
    const float* a_src  = (const float*)d_in[3];
    const float* a_dst  = (const float*)d_in[4];
    const float* W_bcdt = (const float*)d_in[5];
    const float* b_bcdt = (const float*)d_in[6];
    const float* abp_w  = (const float*)d_in[7];
    const float* abp_b  = (const float*)d_in[8];
    const float* cp_w   = (const float*)d_in[9];
    const float* cp_b   = (const float*)d_in[10];
    const float* W_hz   = (const float*)d_in[11];
    const float* b_hz   = (const float*)d_in[12];
    const float* out_w  = (const float*)d_in[13];
    const float* out_b  = (const float*)d_in[14];
    const float* fe1_w  = (const float*)d_in[15];
    const float* fe1_b  = (const float*)d_in[16];
    const float* fe_ln_g= (const float*)d_in[17];
    const float* fe_ln_b= (const float*)d_in[18];
    const float* fe2_w  = (const float*)d_in[19];
    const float* fe2_b  = (const float*)d_in[20];
    const float* Avec   = (const float*)d_in[21];
    const float* Dvec   = (const float*)d_in[22];
    const float* g1_w   = (const float*)d_in[23];
    const float* g1_b   = (const float*)d_in[24];
    const float* g_ln_g = (const float*)d_in[25];
    const float* g_ln_b = (const float*)d_in[26];
    const float* g2_w   = (const float*)d_in[27];
    const float* g2_b   = (const float*)d_in[28];
    const float* ln_g   = (const float*)d_in[29];
    const float* ln_b   = (const float*)d_in[30];
    float* outp = (float*)d_out;

    char* p = (char*)d_ws;
    size_t off = 0;
    auto take = [&](size_t nbytes) -> void* {
        void* r = p + off;
        off += (nbytes + 255) & ~(size_t)255;
        return r;
    };
    ushort* wT    = (ushort*)take(256 * 256 * 2);
    ushort* fe1T  = (ushort*)take(512 * 256 * 2);
    ushort* fe2T  = (ushort*)take(256 * 512 * 2);
    ushort* bcdtT = (ushort*)take(384 * 256 * 2);
    ushort* abpT  = (ushort*)take(256 * 128 * 2);
    ushort* hzT   = (ushort*)take(1024 * 256 * 2);
    ushort* outT  = (ushort*)take(256 * 512 * 2);
    ushort* g1T   = (ushort*)take(512 * 512 * 2);
    ushort* g2T   = (ushort*)take(256 * 512 * 2);
    ushort* hbf   = (ushort*)take((size_t)8192 * 256 * 2);
    float*  Wh    = (float*) take((size_t)8192 * 256 * 4);
    ushort* Whbf  = (ushort*)take((size_t)8192 * 256 * 2);
    ushort* WhT   = (ushort*)take((size_t)8192 * 256 * 2);
    float*  sbuf  = (float*) take(8192 * 4);
    float*  dbuf  = (float*) take(8192 * 4);
    float*  cscl  = (float*) take(8192 * 4);
    float*  hattn = (float*) take((size_t)8192 * 256 * 4);
    float*  henh  = (float*) take((size_t)8192 * 256 * 4);
    float*  BCdt  = (float*) take((size_t)8192 * 384 * 4);  // also lpart, then gl
    ushort* SB    = (ushort*)take((size_t)8192 * 128 * 2);
    ushort* hsbf  = (ushort*)take((size_t)8192 * 256 * 2);
    ushort* vbf   = (ushort*)take((size_t)8192 * 512 * 2);
    float*  hs2   = (float*) take((size_t)8192 * 256 * 4);
    ushort* comb  = (ushort*)take((size_t)8192 * 512 * 2);
    ushort* tact  = (ushort*)take((size_t)8192 * 512 * 2);
    float*  big   = (float*) take((size_t)8192 * 1024 * 4); // Upart / t1 / hz / t2
    float*  gl    = BCdt;      // BCdt dead after ssm_front
    float*  Upart = big;       // 4*8192*256*4 B == big exactly; dead before fe1
    float*  lpart = BCdt;      // 4*8192*4 B = 131 KB; dead before bcdt gemm

    (void)in_sizes; (void)n_in; (void)out_size; (void)ws_size;

    // zero the atomic accumulators for the fused s/d row-dots (sbuf+dbuf contiguous)
    hipMemsetAsync(sbuf, 0, 2 * 8192 * sizeof(float), stream);

    // ALL weight transposes + h cast in one dispatch
    {
        TArgs ta; int boff = 0;
        auto addT = [&](int i, const float* in, ushort* out, int R, int C) {
            ta.j[i] = TJob{in, out, R, C, boff};
            boff += (R / 32) * (C / 32);
        };
        addT(0, W,      wT,    256, 256);
        addT(1, fe1_w,  fe1T,  256, 512);
        addT(2, fe2_w,  fe2T,  512, 256);
        addT(3, W_bcdt, bcdtT, 256, 384);
        addT(4, abp_w,  abpT,  128, 256);
        addT(5, W_hz,   hzT,   256, 1024);
        addT(6, out_w,  outT,  512, 256);
        addT(7, g1_w,   g1T,   512, 512);
        addT(8, g2_w,   g2T,   512, 256);
        ta.j[9] = TJob{h, hbf, 0, 8192 * 256, boff};   // flat cast
        boff += (8192 * 256) / 1024;
        multi_transpose_kernel<<<boff, 256, 0, stream>>>(ta);
    }

    // Wh = h @ W  (f32 + bf16) with fused s = Wh@a_src, d = Wh@a_dst atomics
    gemm_k<256, EPI_WH><<<dim3(128, 4), 256, 0, stream>>>(
        hbf, wT, nullptr, 256, Wh, Whbf, 256, 0, nullptr, a_src, a_dst, sbuf, dbuf);
    transpose_cast_kernel<<<dim3(8, 256), 256, 0, stream>>>(Wh, WhT, 8192, 256);

    // fused GAT attention: barrier-free streaming, 4-way j-split partials
    attn_kernel<<<dim3(128, 4), 256, 0, stream>>>(adj, sbuf, dbuf, WhT, Upart, lpart);
    attn_combine_kernel<<<2048, 256, 0, stream>>>(Upart, lpart, hattn, comb);

    // feature enhancer
    gemm_k<256, EPI_F32><<<dim3(128, 8), 256, 0, stream>>>(
        Whbf, fe1T, fe1_b, 512, big, nullptr, 0, 0, nullptr, nullptr, nullptr, nullptr, nullptr);
    ln_silu_512_kernel<<<2048, 256, 0, stream>>>(big, fe_ln_g, fe_ln_b, tact);
    gemm_k<512, EPI_F32><<<dim3(128, 4), 256, 0, stream>>>(
        tact, fe2T, fe2_b, 256, henh, nullptr, 0, 0, nullptr, nullptr, nullptr, nullptr, nullptr);

    // SSM branch
    gemm_k<256, EPI_F32><<<dim3(128, 6), 256, 0, stream>>>(
        Whbf, bcdtT, b_bcdt, 384, BCdt, nullptr, 0, 0, nullptr, nullptr, nullptr, nullptr, nullptr);
    ssm_front_kernel<<<2048, 256, 0, stream>>>(BCdt, Avec, cp_w, cp_b, SB, cscl);
    gemm_k<128, EPI_MUL_BF16><<<dim3(128, 4), 256, 0, stream>>>(
        SB, abpT, abp_b, 256, nullptr, hsbf, 256, 0, Wh, nullptr, nullptr, nullptr, nullptr);
    gemm_k<256, EPI_F32><<<dim3(128, 16), 256, 0, stream>>>(
        hsbf, hzT, b_hz, 1024, big, nullptr, 0, 0, nullptr, nullptr, nullptr, nullptr, nullptr);
    hz_act_kernel<<<4096, 256, 0, stream>>>(big, Dvec, vbf);
    gemm_k<512, EPI_SCALE_FB><<<dim3(128, 4), 256, 0, stream>>>(
        vbf, outT, out_b, 256, hs2, comb, 512, 256, cscl, nullptr, nullptr, nullptr, nullptr);

    // gated fusion
    gemm_k<512, EPI_F32><<<dim3(128, 8), 256, 0, stream>>>(
        comb, g1T, g1_b, 512, big, nullptr, 0, 0, nullptr, nullptr, nullptr, nullptr, nullptr);
    ln_silu_512_kernel<<<2048, 256, 0, stream>>>(big, g_ln_g, g_ln_b, tact);
    gemm_k<512, EPI_F32><<<dim3(128, 4), 256, 0, stream>>>(
        tact, g2T, g2_b, 256, gl, nullptr, 0, 0, nullptr, nullptr, nullptr, nullptr, nullptr);
    final_kernel<<<2048, 256, 0, stream>>>(gl, hattn, hs2, henh, ln_g, ln_b, outp);
}

// Round 4
// 645.876 us; speedup vs baseline: 1.2776x; 1.2776x over previous
//
#include <hip/hip_runtime.h>
#include <cstdint>

typedef __attribute__((ext_vector_type(8))) short short8;
typedef __attribute__((ext_vector_type(4))) float f32x4;

#define DEVINL static __device__ __forceinline__

DEVINL ushort f2b(float f) {
    uint32_t u = __builtin_bit_cast(uint32_t, f);
    u += 0x7FFFu + ((u >> 16) & 1u);
    return (ushort)(u >> 16);
}

typedef __attribute__((address_space(3))) uint32_t lds_u32;
typedef const __attribute__((address_space(1))) uint32_t glb_u32;

DEVINL void load_lds_16(const ushort* g, ushort* l) {
    __builtin_amdgcn_global_load_lds((glb_u32*)g, (lds_u32*)l, 16, 0, 0);
}

// ---------------------------------------------------------------------------
// bf16 MFMA GEMM v2 (m97-lite): C[M,N] = A[M,K] @ BT[N,K]^T (+bias, epilogues)
// BM=128, BN=64, BK=64. LDS-staged via swizzled global_load_lds (coalesced),
// ds_read_b128 fragments; LDS rows 128B = 8 16B-groups, slot = kgrp ^ (row&7)
// -> quarter-wave lanes land on distinct 4-bank groups, 2-way alias (free).
// Wave w: rows [w*32, w*32+32) (2 row-frags), cols all 64 (4 col-frags).
// ---------------------------------------------------------------------------
constexpr int EPI_F32      = 0;  // outf = acc + bias
constexpr int EPI_MUL_BF16 = 2;  // outb = (acc+bias) * extra[row*N+col]
constexpr int EPI_SCALE_FB = 3;  // v = (acc+bias)*extra[row]; outf & outb
constexpr int EPI_WH       = 4;  // outf+outb AND atomic row-dots vs asrc/adst

template<int K, int EPI>
__global__ __launch_bounds__(256) void gemm_k(
    const ushort* __restrict__ A, const ushort* __restrict__ BT,
    const float* __restrict__ bias, int N,
    float* __restrict__ outf, ushort* __restrict__ outb, int obld, int oboff,
    const float* __restrict__ extra,
    const float* __restrict__ asrc, const float* __restrict__ adst,
    float* __restrict__ sOut, float* __restrict__ dOut)
{
    __shared__ ushort Asm[128 * 64];   // [row][64k], swizzled groups
    __shared__ ushort Bsm[64 * 64];

    const int wave = threadIdx.x >> 6;
    const int lane = threadIdx.x & 63;
    const int quad = lane >> 4;
    const int l16  = lane & 15;
    const int lr   = lane >> 3, ls = lane & 7;   // staging: 8 rows x 8 slots
    const int m0 = blockIdx.x * 128;
    const int n0 = blockIdx.y * 64;

    f32x4 zero = {0.f, 0.f, 0.f, 0.f};
    f32x4 acc[2][4] = {{zero, zero, zero, zero}, {zero, zero, zero, zero}};

    for (int k0 = 0; k0 < K; k0 += 64) {
        // stage A tile 128x64 (4 insts/wave, 8 rows each, swizzled src group)
        #pragma unroll
        for (int p = 0; p < 4; ++p) {
            const int r = wave * 32 + p * 8 + lr;
            load_lds_16(A + (size_t)(m0 + r) * K + k0 + ((ls ^ (r & 7)) * 8),
                        Asm + (size_t)(wave * 32 + p * 8) * 64);
        }
        // stage B tile 64x64 (2 insts/wave)
        #pragma unroll
        for (int p = 0; p < 2; ++p) {
            const int n = wave * 16 + p * 8 + lr;
            load_lds_16(BT + (size_t)(n0 + n) * K + k0 + ((ls ^ (n & 7)) * 8),
                        Bsm + (size_t)(wave * 16 + p * 8) * 64);
        }
        __syncthreads();
        #pragma unroll
        for (int ks = 0; ks < 2; ++ks) {
            const int kg = ks * 4 + quad;
            const int sl = (kg ^ (l16 & 7)) * 8;
            short8 a0 = *(const short8*)(Asm + (wave * 32 + l16) * 64 + sl);
            short8 a1 = *(const short8*)(Asm + (wave * 32 + 16 + l16) * 64 + sl);
            #pragma unroll
            for (int c = 0; c < 4; ++c) {
                short8 bf = *(const short8*)(Bsm + (c * 16 + l16) * 64 + sl);
                acc[0][c] = __builtin_amdgcn_mfma_f32_16x16x32_bf16(a0, bf, acc[0][c], 0, 0, 0);
                acc[1][c] = __builtin_amdgcn_mfma_f32_16x16x32_bf16(a1, bf, acc[1][c], 0, 0, 0);
            }
        }
        __syncthreads();
    }

    #pragma unroll
    for (int it = 0; it < 2; ++it) {
        #pragma unroll
        for (int r = 0; r < 4; ++r) {
            const int row = m0 + wave * 32 + it * 16 + quad * 4 + r;
            float sp = 0.f, dp = 0.f;
            #pragma unroll
            for (int c = 0; c < 4; ++c) {
                const int col = n0 + c * 16 + l16;
                float v = acc[it][c][r] + (bias ? bias[col] : 0.f);
                if (EPI == EPI_MUL_BF16) v *= extra[(size_t)row * N + col];
                if (EPI == EPI_SCALE_FB) v *= extra[row];
                if (EPI == EPI_F32 || EPI == EPI_SCALE_FB || EPI == EPI_WH)
                    outf[(size_t)row * N + col] = v;
                if (EPI == EPI_MUL_BF16 || EPI == EPI_SCALE_FB || EPI == EPI_WH)
                    outb[(size_t)row * obld + oboff + col] = f2b(v);
                if (EPI == EPI_WH) { sp += v * asrc[col]; dp += v * adst[col]; }
            }
            if (EPI == EPI_WH) {
                #pragma unroll
                for (int o = 1; o < 16; o <<= 1) {
                    sp += __shfl_xor(sp, o);
                    dp += __shfl_xor(dp, o);
                }
                if (l16 == 0) {
                    atomicAdd(&sOut[row], sp);
                    atomicAdd(&dOut[row], dp);
                }
            }
        }
    }
}

// ---------------------------------------------------------------------------
// Fused GAT attention v4: round-2 LDS structure, 2x work per barrier.
// Block: 64 i-rows, j-slab = blockIdx.y*2048, chunks of 64 j.
// vsm: WhT slice [256 f][64 j] bf16 (32 KB), swizzled slot = jgrp ^ (f&7),
// staged by global_load_lds (8 insts/wave). wsm: P tile [64 i][64 j] (8 KB),
// same swizzle, written by P-compute (4 thr/row, coalesced 32B adj reads).
// Wave (rt=w&1, ch=w>>1): rows rt*32..+32 (2 A-frags), cols ch*128..+128
// (8 B-tiles) -> 32 MFMA/chunk/wave. Partials Upart/lpart, combined later.
// ---------------------------------------------------------------------------
__global__ __launch_bounds__(256) void attn_kernel(
    const int* __restrict__ adj, const float* __restrict__ sA,
    const float* __restrict__ dA, const ushort* __restrict__ WhT,
    float* __restrict__ Upart, float* __restrict__ lpart)
{
    __shared__ ushort vsm[256 * 64];
    __shared__ ushort wsm[64 * 64];

    const int tid  = threadIdx.x;
    const int wave = tid >> 6, lane = tid & 63, quad = lane >> 4, l16 = lane & 15;
    const int lr = lane >> 3, ls = lane & 7;
    const int i0 = blockIdx.x * 64;
    const int js = blockIdx.y;
    const int jbase = js * 2048;
    // P-compute mapping: 4 threads per row, 2 groups of 8 j each
    const int pr = tid >> 2, pc = tid & 3;
    const float s_r = sA[i0 + pr];
    const int* adjp = adj + (size_t)(i0 + pr) * 8192 + jbase;
    const int rt = wave & 1, ch = wave >> 1;

    f32x4 zero = {0.f, 0.f, 0.f, 0.f};
    f32x4 acc[2][8] = {{zero, zero, zero, zero, zero, zero, zero, zero},
                       {zero, zero, zero, zero, zero, zero, zero, zero}};
    float lsum = 0.f;

    for (int c64 = 0; c64 < 2048; c64 += 64) {
        // async stage WhT[f 0..256)[j c64..c64+64) -> vsm (8 insts/wave)
        #pragma unroll
        for (int p = 0; p < 8; ++p) {
            const int f = wave * 64 + p * 8 + lr;
            load_lds_16(WhT + (size_t)f * 8192 + jbase + c64 + ((ls ^ (f & 7)) * 8),
                        vsm + (size_t)(wave * 64 + p * 8) * 64);
        }
        // P tile 64x64: thread handles groups {pc, pc+4} of row pr
        #pragma unroll
        for (int gi = 0; gi < 2; ++gi) {
            const int g = pc + gi * 4;
            const int4   a0 = *(const int4*)  (adjp + c64 + g * 8);
            const int4   a1 = *(const int4*)  (adjp + c64 + g * 8 + 4);
            const float4 d0 = *(const float4*)(dA + jbase + c64 + g * 8);
            const float4 d1 = *(const float4*)(dA + jbase + c64 + g * 8 + 4);
            const int   aa[8] = {a0.x, a0.y, a0.z, a0.w, a1.x, a1.y, a1.z, a1.w};
            const float dd[8] = {d0.x, d0.y, d0.z, d0.w, d1.x, d1.y, d1.z, d1.w};
            union { ushort us[8]; uint4 v; } pk;
            #pragma unroll
            for (int q = 0; q < 8; ++q) {
                float e = s_r + dd[q];
                e = fmaxf(e, 0.2f * e);              // leaky_relu(0.2)
                const float w = aa[q] ? __expf(e) : 0.f;
                lsum += w; pk.us[q] = f2b(w);
            }
            *(uint4*)(wsm + pr * 64 + ((g ^ (pr & 7)) * 8)) = pk.v;
        }
        __syncthreads();   // drains DMA + wsm writes

        #pragma unroll
        for (int ks = 0; ks < 2; ++ks) {
            const int kg = ks * 4 + quad;
            const int sl = (kg ^ (l16 & 7)) * 8;
            short8 a0 = *(const short8*)(wsm + (rt * 32 + l16) * 64 + sl);
            short8 a1 = *(const short8*)(wsm + (rt * 32 + 16 + l16) * 64 + sl);
            #pragma unroll
            for (int c = 0; c < 8; ++c) {
                short8 bf = *(const short8*)(vsm + (ch * 128 + c * 16 + l16) * 64 + sl);
                acc[0][c] = __builtin_amdgcn_mfma_f32_16x16x32_bf16(a0, bf, acc[0][c], 0, 0, 0);
                acc[1][c] = __builtin_amdgcn_mfma_f32_16x16x32_bf16(a1, bf, acc[1][c], 0, 0, 0);
            }
        }
        __syncthreads();
    }

    // row sum: fold the 4 threads sharing row pr (consecutive lanes)
    lsum += __shfl_down(lsum, 1);
    lsum += __shfl_down(lsum, 2);
    if (pc == 0) lpart[(size_t)js * 8192 + i0 + pr] = lsum;

    #pragma unroll
    for (int it = 0; it < 2; ++it) {
        #pragma unroll
        for (int c = 0; c < 8; ++c) {
            const int col = ch * 128 + c * 16 + l16;
            #pragma unroll
            for (int r = 0; r < 4; ++r) {
                const int row = i0 + rt * 32 + it * 16 + quad * 4 + r;
                Upart[((size_t)js * 8192 + row) * 256 + col] = acc[it][c][r];
            }
        }
    }
}

// combine: h_attn = (sum_js U) / (sum_js l); write f32 + comb[:,0:256] bf16
__global__ __launch_bounds__(256) void attn_combine_kernel(
    const float* __restrict__ Upart, const float* __restrict__ lpart,
    float* __restrict__ outf, ushort* __restrict__ outb)
{
    const int row = blockIdx.x * 4 + (threadIdx.x >> 6);
    const int lane = threadIdx.x & 63;
    float l = 0.f;
    #pragma unroll
    for (int js = 0; js < 4; ++js) l += lpart[(size_t)js * 8192 + row];
    const float inv = 1.f / l;
    #pragma unroll
    for (int i = 0; i < 4; ++i) {
        const int c = i * 64 + lane;
        float u = 0.f;
        #pragma unroll
        for (int js = 0; js < 4; ++js)
            u += Upart[((size_t)js * 8192 + row) * 256 + c];
        const float v = u * inv;
        outf[(size_t)row * 256 + c] = v;
        outb[(size_t)row * 512 + c] = f2b(v);
    }
}

// ---------------------------------------------------------------------------
// Descriptor-driven transpose/cast mega-kernel (all weights + h cast, 1 dispatch)
// ---------------------------------------------------------------------------
struct TJob { const float* in; ushort* out; int R, C, off; };
struct TArgs { TJob j[10]; };

__global__ __launch_bounds__(256) void multi_transpose_kernel(TArgs a)
{
    __shared__ float tile[32][33];
    const int b = blockIdx.x;
    int ji = 0;
    #pragma unroll
    for (int k = 1; k < 10; ++k) if (b >= a.j[k].off) ji = k;
    const TJob J = a.j[ji];
    const int t = b - J.off;

    if (J.R == 0) {            // flat cast
        const int base = t * 1024 + threadIdx.x;
        #pragma unroll
        for (int k = 0; k < 4; ++k)
            J.out[base + k * 256] = f2b(J.in[base + k * 256]);
        return;
    }
    const int CB = J.C >> 5;
    const int bx = t % CB, by = t / CB;
    const int tx = threadIdx.x & 31, ty = threadIdx.x >> 5;
    const int c0 = bx * 32, r0 = by * 32;
    #pragma unroll
    for (int i = ty; i < 32; i += 8)
        tile[i][tx] = J.in[(size_t)(r0 + i) * J.C + (c0 + tx)];
    __syncthreads();
    #pragma unroll
    for (int i = ty; i < 32; i += 8)
        J.out[(size_t)(c0 + i) * J.R + (r0 + tx)] = f2b(tile[tx][i]);
}

// f32 [R][C] -> bf16 [C][R]  (Wh -> WhT, mid-pipeline)
__global__ __launch_bounds__(256) void transpose_cast_kernel(
    const float* __restrict__ in, ushort* __restrict__ out, int R, int C)
{
    __shared__ float tile[32][33];
    const int tx = threadIdx.x & 31, ty = threadIdx.x >> 5;
    const int c0 = blockIdx.x * 32, r0 = blockIdx.y * 32;
    #pragma unroll
    for (int i = ty; i < 32; i += 8)
        tile[i][tx] = in[(size_t)(r0 + i) * C + (c0 + tx)];
    __syncthreads();
    #pragma unroll
    for (int i = ty; i < 32; i += 8)
        out[(size_t)(c0 + i) * R + (r0 + tx)] = f2b(tile[tx][i]);
}

// LayerNorm(512) + silu -> bf16 (wave per row)
__global__ __launch_bounds__(256) void ln_silu_512_kernel(
    const float* __restrict__ in, const float* __restrict__ g,
    const float* __restrict__ b, ushort* __restrict__ outb)
{
    const int row = blockIdx.x * 4 + (threadIdx.x >> 6);
    const int lane = threadIdx.x & 63;
    const size_t base = (size_t)row * 512;
    float x[8]; float sum = 0.f, sq = 0.f;
    #pragma unroll
    for (int i = 0; i < 8; ++i) {
        const float v = in[base + i * 64 + lane];
        x[i] = v; sum += v; sq += v * v;
    }
    #pragma unroll
    for (int o = 32; o; o >>= 1) { sum += __shfl_xor(sum, o); sq += __shfl_xor(sq, o); }
    const float mean = sum * (1.f / 512.f);
    const float var  = sq * (1.f / 512.f) - mean * mean;
    const float rstd = rsqrtf(var + 1e-5f);
    #pragma unroll
    for (int i = 0; i < 8; ++i) {
        const int c = i * 64 + lane;
        const float y = (x[i] - mean) * rstd * g[c] + b[c];
        outb[base + c] = f2b(y / (1.f + __expf(-y)));   // silu
    }
}

// SSM front: softmax(dt+A)*B -> SB bf16; cscale = 1 + C@cp_w + cp_b
__global__ __launch_bounds__(256) void ssm_front_kernel(
    const float* __restrict__ BCdt, const float* __restrict__ Avec,
    const float* __restrict__ cpw, const float* __restrict__ cpb,
    ushort* __restrict__ SB, float* __restrict__ cscale)
{
    const int row = blockIdx.x * 4 + (threadIdx.x >> 6);
    const int lane = threadIdx.x & 63;
    const float* rp = BCdt + (size_t)row * 384;
    const float B0 = rp[lane],       B1 = rp[64 + lane];
    const float C0 = rp[128 + lane], C1 = rp[192 + lane];
    float t0 = rp[256 + lane] + Avec[lane];
    float t1 = rp[320 + lane] + Avec[64 + lane];
    float mx = fmaxf(t0, t1);
    #pragma unroll
    for (int o = 32; o; o >>= 1) mx = fmaxf(mx, __shfl_xor(mx, o));
    const float e0 = __expf(t0 - mx), e1 = __expf(t1 - mx);
    float ssum = e0 + e1;
    #pragma unroll
    for (int o = 32; o; o >>= 1) ssum += __shfl_xor(ssum, o);
    const float inv = 1.f / ssum;
    SB[(size_t)row * 128 + lane]      = f2b(e0 * inv * B0);
    SB[(size_t)row * 128 + 64 + lane] = f2b(e1 * inv * B1);
    float cp = C0 * cpw[lane] + C1 * cpw[64 + lane];
    #pragma unroll
    for (int o = 32; o; o >>= 1) cp += __shfl_xor(cp, o);
    if (lane == 0) cscale[row] = 1.f + cp + cpb[0];
}

// v = h_part * (silu(z) + D) from hz[8192,1024] -> bf16 [8192,512]
__global__ void hz_act_kernel(const float* __restrict__ hz,
                              const float* __restrict__ Dp, ushort* __restrict__ out)
{
    const float D0 = Dp[0];
    const int n = 8192 * 512;
    for (int i = blockIdx.x * blockDim.x + threadIdx.x; i < n; i += gridDim.x * blockDim.x) {
        const int r = i >> 9, c = i & 511;
        const float hp = hz[(size_t)r * 1024 + c];
        const float z  = hz[(size_t)r * 1024 + 512 + c];
        out[i] = f2b(hp * (z / (1.f + __expf(-z)) + D0));
    }
}

// g = sigmoid(gl); fused = g*ha + (1-g)*hs2 + he; LayerNorm(256) -> out f32
__global__ __launch_bounds__(256) void final_kernel(
    const float* __restrict__ gl, const float* __restrict__ ha,
    const float* __restrict__ hs2, const float* __restrict__ he,
    const float* __restrict__ lng, const float* __restrict__ lnb,
    float* __restrict__ outp)
{
    const int row = blockIdx.x * 4 + (threadIdx.x >> 6);
    const int lane = threadIdx.x & 63;
    const size_t base = (size_t)row * 256;
    float f[4]; float sum = 0.f, sq = 0.f;
    #pragma unroll
    for (int i = 0; i < 4; ++i) {
        const int c = i * 64 + lane;
        const float gv = 1.f / (1.f + __expf(-gl[base + c]));
        const float v = gv * ha[base + c] + (1.f - gv) * hs2[base + c] + he[base + c];
        f[i] = v; sum += v; sq += v * v;
    }
    #pragma unroll
    for (int o = 32; o; o >>= 1) { sum += __shfl_xor(sum, o); sq += __shfl_xor(sq, o); }
    const float mean = sum * (1.f / 256.f);
    const float var  = sq * (1.f / 256.f) - mean * mean;
    const float rstd = rsqrtf(var + 1e-5f);
    #pragma unroll
    for (int i = 0; i < 4; ++i) {
        const int c = i * 64 + lane;
        outp[base + c] = (f[i] - mean) * rstd * lng[c] + lnb[c];
    }
}

// ---------------------------------------------------------------------------
extern "C" void kernel_launch(void* const* d_in, const int* in_sizes, int n_in,
                              void* d_out, int out_size, void* d_ws, size_t ws_size,
                              hipStream_t stream)
{
    const float* h      = (const float*)d_in[0];
    const int*   adj    = (const int*)  d_in[1];
    const float* W      = (const float*)d_in[2];
    const float* a_src  = (const float*)d_in[3];
    const float* a_dst  = (const float*)d_in[4];
    const float* W_bcdt = (const float*)d_in[5];
    const float* b_bcdt = (const float*)d_in[6];
    const float* abp_w  = (const float*)d_in[7];
    const float* abp_b  = (const float*)d_in[8];
    const float* cp_w   = (const float*)d_in[9];
    const float* cp_b   = (const float*)d_in[10];
    const float* W_hz   = (const float*)d_in[11];
    const float* b_hz   = (const float*)d_in[12];
    const float* out_w  = (const float*)d_in[13];
    const float* out_b  = (const float*)d_in[14];
    const float* fe1_w  = (const float*)d_in[15];
    const float* fe1_b  = (const float*)d_in[16];
    const float* fe_ln_g= (const float*)d_in[17];
    const float* fe_ln_b= (const float*)d_in[18];
    const float* fe2_w  = (const float*)d_in[19];
    const float* fe2_b  = (const float*)d_in[20];
    const float* Avec   = (const float*)d_in[21];
    const float* Dvec   = (const float*)d_in[22];
    const float* g1_w   = (const float*)d_in[23];
    const float* g1_b   = (const float*)d_in[24];
    const float* g_ln_g = (const float*)d_in[25];
    const float* g_ln_b = (const float*)d_in[26];
    const float* g2_w   = (const float*)d_in[27];
    const float* g2_b   = (const float*)d_in[28];
    const float* ln_g   = (const float*)d_in[29];
    const float* ln_b   = (const float*)d_in[30];
    float* outp = (float*)d_out;

    char* p = (char*)d_ws;
    size_t off = 0;
    auto take = [&](size_t nbytes) -> void* {
        void* r = p + off;
        off += (nbytes + 255) & ~(size_t)255;
        return r;
    };
    ushort* wT    = (ushort*)take(256 * 256 * 2);
    ushort* fe1T  = (ushort*)take(512 * 256 * 2);
    ushort* fe2T  = (ushort*)take(256 * 512 * 2);
    ushort* bcdtT = (ushort*)take(384 * 256 * 2);
    ushort* abpT  = (ushort*)take(256 * 128 * 2);
    ushort* hzT   = (ushort*)take(1024 * 256 * 2);
    ushort* outT  = (ushort*)take(256 * 512 * 2);
    ushort* g1T   = (ushort*)take(512 * 512 * 2);
    ushort* g2T   = (ushort*)take(256 * 512 * 2);
    ushort* hbf   = (ushort*)take((size_t)8192 * 256 * 2);
    float*  Wh    = (float*) take((size_t)8192 * 256 * 4);
    ushort* Whbf  = (ushort*)take((size_t)8192 * 256 * 2);
    ushort* WhT   = (ushort*)take((size_t)8192 * 256 * 2);
    float*  sbuf  = (float*) take(8192 * 4);
    float*  dbuf  = (float*) take(8192 * 4);
    float*  cscl  = (float*) take(8192 * 4);
    float*  hattn = (float*) take((size_t)8192 * 256 * 4);
    float*  henh  = (float*) take((size_t)8192 * 256 * 4);
    float*  BCdt  = (float*) take((size_t)8192 * 384 * 4);  // also lpart, then gl
    ushort* SB    = (ushort*)take((size_t)8192 * 128 * 2);
    ushort* hsbf  = (ushort*)take((size_t)8192 * 256 * 2);
    ushort* vbf   = (ushort*)take((size_t)8192 * 512 * 2);
    float*  hs2   = (float*) take((size_t)8192 * 256 * 4);
    ushort* comb  = (ushort*)take((size_t)8192 * 512 * 2);
    ushort* tact  = (ushort*)take((size_t)8192 * 512 * 2);
    float*  big   = (float*) take((size_t)8192 * 1024 * 4); // Upart / t1 / hz / t2
    float*  gl    = BCdt;      // BCdt dead after ssm_front
    float*  Upart = big;       // 4*8192*256*4 B == big; consumed by combine pre-fe1
    float*  lpart = BCdt;      // 4*8192*4 B; dead before bcdt gemm

    (void)in_sizes; (void)n_in; (void)out_size; (void)ws_size;

    // zero the atomic accumulators for the fused s/d row-dots
    hipMemsetAsync(sbuf, 0, 2 * 8192 * sizeof(float), stream);

    // ALL weight transposes + h cast in one dispatch
    {
        TArgs ta; int boff = 0;
        auto addT = [&](int i, const float* in, ushort* out, int R, int C) {
            ta.j[i] = TJob{in, out, R, C, boff};
            boff += (R / 32) * (C / 32);
        };
        addT(0, W,      wT,    256, 256);
        addT(1, fe1_w,  fe1T,  256, 512);
        addT(2, fe2_w,  fe2T,  512, 256);
        addT(3, W_bcdt, bcdtT, 256, 384);
        addT(4, abp_w,  abpT,  128, 256);
        addT(5, W_hz,   hzT,   256, 1024);
        addT(6, out_w,  outT,  512, 256);
        addT(7, g1_w,   g1T,   512, 512);
        addT(8, g2_w,   g2T,   512, 256);
        ta.j[9] = TJob{h, hbf, 0, 8192 * 256, boff};   // flat cast
        boff += (8192 * 256) / 1024;
        multi_transpose_kernel<<<boff, 256, 0, stream>>>(ta);
    }

    // Wh = h @ W  (f32 + bf16) with fused s/d row-dot atomics
    gemm_k<256, EPI_WH><<<dim3(64, 4), 256, 0, stream>>>(
        hbf, wT, nullptr, 256, Wh, Whbf, 256, 0, nullptr, a_src, a_dst, sbuf, dbuf);
    transpose_cast_kernel<<<dim3(8, 256), 256, 0, stream>>>(Wh, WhT, 8192, 256);

    // fused GAT attention: LDS-staged, 4-way j-split partials
    attn_kernel<<<dim3(128, 4), 256, 0, stream>>>(adj, sbuf, dbuf, WhT, Upart, lpart);
    attn_combine_kernel<<<2048, 256, 0, stream>>>(Upart, lpart, hattn, comb);

    // feature enhancer
    gemm_k<256, EPI_F32><<<dim3(64, 8), 256, 0, stream>>>(
        Whbf, fe1T, fe1_b, 512, big, nullptr, 0, 0, nullptr, nullptr, nullptr, nullptr, nullptr);
    ln_silu_512_kernel<<<2048, 256, 0, stream>>>(big, fe_ln_g, fe_ln_b, tact);
    gemm_k<512, EPI_F32><<<dim3(64, 4), 256, 0, stream>>>(
        tact, fe2T, fe2_b, 256, henh, nullptr, 0, 0, nullptr, nullptr, nullptr, nullptr, nullptr);

    // SSM branch
    gemm_k<256, EPI_F32><<<dim3(64, 6), 256, 0, stream>>>(
        Whbf, bcdtT, b_bcdt, 384, BCdt, nullptr, 0, 0, nullptr, nullptr, nullptr, nullptr, nullptr);
    ssm_front_kernel<<<2048, 256, 0, stream>>>(BCdt, Avec, cp_w, cp_b, SB, cscl);
    gemm_k<128, EPI_MUL_BF16><<<dim3(64, 4), 256, 0, stream>>>(
        SB, abpT, abp_b, 256, nullptr, hsbf, 256, 0, Wh, nullptr, nullptr, nullptr, nullptr);
    gemm_k<256, EPI_F32><<<dim3(64, 16), 256, 0, stream>>>(
        hsbf, hzT, b_hz, 1024, big, nullptr, 0, 0, nullptr, nullptr, nullptr, nullptr, nullptr);
    hz_act_kernel<<<4096, 256, 0, stream>>>(big, Dvec, vbf);
    gemm_k<512, EPI_SCALE_FB><<<dim3(64, 4), 256, 0, stream>>>(
        vbf, outT, out_b, 256, hs2, comb, 512, 256, cscl, nullptr, nullptr, nullptr, nullptr);

    // gated fusion
    gemm_k<512, EPI_F32><<<dim3(64, 8), 256, 0, stream>>>(
        comb, g1T, g1_b, 512, big, nullptr, 0, 0, nullptr, nullptr, nullptr, nullptr, nullptr);
    ln_silu_512_kernel<<<2048, 256, 0, stream>>>(big, g_ln_g, g_ln_b, tact);
    gemm_k<512, EPI_F32><<<dim3(64, 4), 256, 0, stream>>>(
        tact, g2T, g2_b, 256, gl, nullptr, 0, 0, nullptr, nullptr, nullptr, nullptr, nullptr);
    final_kernel<<<2048, 256, 0, stream>>>(gl, hattn, hs2, henh, ln_g, ln_b, outp);
}

// Round 5
// 611.158 us; speedup vs baseline: 1.3502x; 1.0568x over previous
//
#include <hip/hip_runtime.h>
#include <cstdint>

typedef __attribute__((ext_vector_type(8))) short short8;
typedef __attribute__((ext_vector_type(4))) float f32x4;

#define DEVINL static __device__ __forceinline__

DEVINL ushort f2b(float f) {
    uint32_t u = __builtin_bit_cast(uint32_t, f);
    u += 0x7FFFu + ((u >> 16) & 1u);
    return (ushort)(u >> 16);
}

typedef __attribute__((address_space(3))) uint32_t lds_u32;
typedef const __attribute__((address_space(1))) uint32_t glb_u32;

DEVINL void load_lds_16(const ushort* g, ushort* l) {
    __builtin_amdgcn_global_load_lds((glb_u32*)g, (lds_u32*)l, 16, 0, 0);
}

// ---------------------------------------------------------------------------
// gemm_k: C[M,N] = A[M,K] @ BT[N,K]^T (+bias, epilogues). BM=64, BN=64.
// LDS-staged (swizzled global_load_lds, slot = kgrp ^ (row&7)); grid (M/64,N/64).
// ---------------------------------------------------------------------------
constexpr int EPI_F32      = 0;  // outf = acc + bias
constexpr int EPI_MUL_BF16 = 2;  // outb = (acc+bias) * extra[row*N+col]
constexpr int EPI_SCALE_FB = 3;  // v = (acc+bias)*extra[row]; outf & outb
constexpr int EPI_WH       = 4;  // outf+outb AND atomic row-dots vs asrc/adst

template<int K, int EPI>
__global__ __launch_bounds__(256) void gemm_k(
    const ushort* __restrict__ A, const ushort* __restrict__ BT,
    const float* __restrict__ bias, int N,
    float* __restrict__ outf, ushort* __restrict__ outb, int obld, int oboff,
    const float* __restrict__ extra,
    const float* __restrict__ asrc, const float* __restrict__ adst,
    float* __restrict__ sOut, float* __restrict__ dOut)
{
    __shared__ ushort Asm[64 * 64];
    __shared__ ushort Bsm[64 * 64];

    const int wave = threadIdx.x >> 6;
    const int lane = threadIdx.x & 63;
    const int quad = lane >> 4, l16 = lane & 15;
    const int lr = lane >> 3, ls = lane & 7;
    const int m0 = blockIdx.x * 64;
    const int n0 = blockIdx.y * 64;

    f32x4 zero = {0.f, 0.f, 0.f, 0.f};
    f32x4 acc[4] = {zero, zero, zero, zero};

    for (int k0 = 0; k0 < K; k0 += 64) {
        #pragma unroll
        for (int p = 0; p < 2; ++p) {
            const int r = wave * 16 + p * 8 + lr;
            load_lds_16(A + (size_t)(m0 + r) * K + k0 + ((ls ^ (r & 7)) * 8),
                        Asm + (size_t)(wave * 16 + p * 8) * 64);
            load_lds_16(BT + (size_t)(n0 + r) * K + k0 + ((ls ^ (r & 7)) * 8),
                        Bsm + (size_t)(wave * 16 + p * 8) * 64);
        }
        __syncthreads();
        #pragma unroll
        for (int ks = 0; ks < 2; ++ks) {
            const int sl = ((ks * 4 + quad) ^ (l16 & 7)) * 8;
            short8 af = *(const short8*)(Asm + (wave * 16 + l16) * 64 + sl);
            #pragma unroll
            for (int c = 0; c < 4; ++c) {
                short8 bf = *(const short8*)(Bsm + (c * 16 + l16) * 64 + sl);
                acc[c] = __builtin_amdgcn_mfma_f32_16x16x32_bf16(af, bf, acc[c], 0, 0, 0);
            }
        }
        __syncthreads();
    }

    #pragma unroll
    for (int r = 0; r < 4; ++r) {
        const int row = m0 + wave * 16 + quad * 4 + r;
        float sp = 0.f, dp = 0.f;
        #pragma unroll
        for (int c = 0; c < 4; ++c) {
            const int col = n0 + c * 16 + l16;
            float v = acc[c][r] + (bias ? bias[col] : 0.f);
            if (EPI == EPI_MUL_BF16) v *= extra[(size_t)row * N + col];
            if (EPI == EPI_SCALE_FB) v *= extra[row];
            if (EPI == EPI_F32 || EPI == EPI_SCALE_FB || EPI == EPI_WH)
                outf[(size_t)row * N + col] = v;
            if (EPI == EPI_MUL_BF16 || EPI == EPI_SCALE_FB || EPI == EPI_WH)
                outb[(size_t)row * obld + oboff + col] = f2b(v);
            if (EPI == EPI_WH) { sp += v * asrc[col]; dp += v * adst[col]; }
        }
        if (EPI == EPI_WH) {
            #pragma unroll
            for (int o = 1; o < 16; o <<= 1) {
                sp += __shfl_xor(sp, o);
                dp += __shfl_xor(dp, o);
            }
            if (l16 == 0) {
                atomicAdd(&sOut[row], sp);
                atomicAdd(&dOut[row], dp);
            }
        }
    }
}

// ---------------------------------------------------------------------------
// gemm_row: BM=16 rows/block, FULL N per block -> row-local fused epilogues.
// Grid x = M/16 = 512 (2 blocks/CU). 4 waves: wave w covers col-frags
// w*NF..+NF (contiguous) or interleaved w+4c (BCDT, so B<->dt pairs are
// register-local). Cross-wave row reductions via tiny LDS `red`.
// ---------------------------------------------------------------------------
constexpr int EPR_LNSILU = 0;  // outb = silu(LN(acc+bias)) bf16 [M][N]
constexpr int EPR_BCDT   = 1;  // N=384: SB=softmax(dt+A)*B -> outb[M][128]; cscale -> outf
constexpr int EPR_HZ     = 2;  // N=512/half: outb = (h+bh)*(silu(z+bz)+D) bf16 [M][512]
constexpr int EPR_FINAL  = 3;  // g=sigmoid(acc+bias); LN(g*ha+(1-g)*hs2+he) -> outf

template<int K, int N, int EPI>
__global__ __launch_bounds__(256) void gemm_row(
    const ushort* __restrict__ A, const ushort* __restrict__ BT,
    const float* __restrict__ bias,
    float* __restrict__ outf, ushort* __restrict__ outb,
    const float* __restrict__ q0, const float* __restrict__ q1,
    const float* __restrict__ q2, const float* __restrict__ q3,
    const float* __restrict__ q4)
{
    constexpr int NW = N / 4;     // cols per wave
    constexpr int NF = NW / 16;   // col frags per wave
    __shared__ ushort Asm[16 * 64];
    __shared__ ushort Bsm[N * 64];
    __shared__ float red[192];

    const int wave = threadIdx.x >> 6;
    const int lane = threadIdx.x & 63;
    const int quad = lane >> 4, l16 = lane & 15;
    const int lr = lane >> 3, ls = lane & 7;
    const int m0 = blockIdx.x * 16;
    const ushort* Bb = BT + (EPI == EPR_HZ ? (size_t)blockIdx.y * 512 * K : 0);

    f32x4 zero = {0.f, 0.f, 0.f, 0.f};
    f32x4 acc[NF];
    #pragma unroll
    for (int c = 0; c < NF; ++c) acc[c] = zero;

    for (int k0 = 0; k0 < K; k0 += 64) {
        if (wave < 2) {
            const int r = wave * 8 + lr;
            load_lds_16(A + (size_t)(m0 + r) * K + k0 + ((ls ^ (r & 7)) * 8),
                        Asm + (size_t)(wave * 8) * 64);
        }
        #pragma unroll
        for (int p = 0; p < NW / 8; ++p) {
            const int n = wave * NW + p * 8 + lr;
            load_lds_16(Bb + (size_t)n * K + k0 + ((ls ^ (n & 7)) * 8),
                        Bsm + (size_t)(wave * NW + p * 8) * 64);
        }
        __syncthreads();
        #pragma unroll
        for (int ks = 0; ks < 2; ++ks) {
            const int sl = ((ks * 4 + quad) ^ (l16 & 7)) * 8;
            short8 af = *(const short8*)(Asm + l16 * 64 + sl);
            #pragma unroll
            for (int c = 0; c < NF; ++c) {
                const int gf = (EPI == EPR_BCDT) ? (wave + 4 * c) : (wave * NF + c);
                short8 bf = *(const short8*)(Bsm + (gf * 16 + l16) * 64 + sl);
                acc[c] = __builtin_amdgcn_mfma_f32_16x16x32_bf16(af, bf, acc[c], 0, 0, 0);
            }
        }
        __syncthreads();
    }

    // generic bias add (HZ does its own permuted-bias mapping)
    if constexpr (EPI != EPR_HZ) {
        #pragma unroll
        for (int c = 0; c < NF; ++c) {
            const int gf = (EPI == EPR_BCDT) ? (wave + 4 * c) : (wave * NF + c);
            const float bs = bias[gf * 16 + l16];
            #pragma unroll
            for (int r = 0; r < 4; ++r) acc[c][r] += bs;
        }
    }

    if constexpr (EPI == EPR_LNSILU) {
        float s[4], q[4];
        #pragma unroll
        for (int r = 0; r < 4; ++r) {
            s[r] = 0.f; q[r] = 0.f;
            #pragma unroll
            for (int c = 0; c < NF; ++c) { const float v = acc[c][r]; s[r] += v; q[r] += v * v; }
            #pragma unroll
            for (int o = 1; o < 16; o <<= 1) { s[r] += __shfl_xor(s[r], o); q[r] += __shfl_xor(q[r], o); }
        }
        if (l16 == 0) {
            #pragma unroll
            for (int r = 0; r < 4; ++r) {
                red[(quad * 4 + r) * 8 + wave * 2]     = s[r];
                red[(quad * 4 + r) * 8 + wave * 2 + 1] = q[r];
            }
        }
        __syncthreads();
        #pragma unroll
        for (int r = 0; r < 4; ++r) {
            const int row16 = quad * 4 + r;
            float S = 0.f, Q = 0.f;
            #pragma unroll
            for (int w = 0; w < 4; ++w) { S += red[row16 * 8 + w * 2]; Q += red[row16 * 8 + w * 2 + 1]; }
            const float mean = S * (1.f / N);
            const float rstd = rsqrtf(Q * (1.f / N) - mean * mean + 1e-5f);
            #pragma unroll
            for (int c = 0; c < NF; ++c) {
                const int col = (wave * NF + c) * 16 + l16;
                const float y = (acc[c][r] - mean) * rstd * q0[col] + q1[col];
                outb[(size_t)(m0 + row16) * N + col] = f2b(y / (1.f + __expf(-y)));
            }
        }
    } else if constexpr (EPI == EPR_BCDT) {
        // frags: c=0,1 -> B (cols 0..128); c=2,3 -> C; c=4,5 -> dt; pairs B c <-> dt c+4
        float t[2][4], e[2][4];
        #pragma unroll
        for (int ci = 0; ci < 2; ++ci) {
            const int dcol = (wave + 4 * (ci + 4)) * 16 - 256 + l16;
            const float av = q0[dcol];
            #pragma unroll
            for (int r = 0; r < 4; ++r) t[ci][r] = acc[ci + 4][r] + av;
        }
        float pm[4];
        #pragma unroll
        for (int r = 0; r < 4; ++r) {
            pm[r] = fmaxf(t[0][r], t[1][r]);
            #pragma unroll
            for (int o = 1; o < 16; o <<= 1) pm[r] = fmaxf(pm[r], __shfl_xor(pm[r], o));
        }
        if (l16 == 0) {
            #pragma unroll
            for (int r = 0; r < 4; ++r) red[(quad * 4 + r) * 4 + wave] = pm[r];
        }
        __syncthreads();
        float mx[4];
        #pragma unroll
        for (int r = 0; r < 4; ++r) {
            const int row16 = quad * 4 + r;
            mx[r] = fmaxf(fmaxf(red[row16 * 4], red[row16 * 4 + 1]),
                          fmaxf(red[row16 * 4 + 2], red[row16 * 4 + 3]));
        }
        float pe[4], pc[4];
        #pragma unroll
        for (int r = 0; r < 4; ++r) {
            e[0][r] = __expf(t[0][r] - mx[r]);
            e[1][r] = __expf(t[1][r] - mx[r]);
            pe[r] = e[0][r] + e[1][r];
            pc[r] = 0.f;
            #pragma unroll
            for (int ci = 0; ci < 2; ++ci) {
                const int ccol = (wave + 4 * (ci + 2)) * 16 - 128 + l16;
                pc[r] += acc[ci + 2][r] * q1[ccol];
            }
            #pragma unroll
            for (int o = 1; o < 16; o <<= 1) { pe[r] += __shfl_xor(pe[r], o); pc[r] += __shfl_xor(pc[r], o); }
        }
        if (l16 == 0) {
            #pragma unroll
            for (int r = 0; r < 4; ++r) {
                red[64  + (quad * 4 + r) * 4 + wave] = pe[r];
                red[128 + (quad * 4 + r) * 4 + wave] = pc[r];
            }
        }
        __syncthreads();
        #pragma unroll
        for (int r = 0; r < 4; ++r) {
            const int row16 = quad * 4 + r;
            const float inv = 1.f / (red[64 + row16 * 4] + red[64 + row16 * 4 + 1] +
                                     red[64 + row16 * 4 + 2] + red[64 + row16 * 4 + 3]);
            #pragma unroll
            for (int ci = 0; ci < 2; ++ci) {
                const int bcol = (wave + 4 * ci) * 16 + l16;
                outb[(size_t)(m0 + row16) * 128 + bcol] = f2b(acc[ci][r] * e[ci][r] * inv);
            }
        }
        if (wave == 0 && l16 == 0) {
            #pragma unroll
            for (int r = 0; r < 4; ++r) {
                const int row16 = quad * 4 + r;
                outf[m0 + row16] = 1.f + red[128 + row16 * 4] + red[128 + row16 * 4 + 1] +
                                   red[128 + row16 * 4 + 2] + red[128 + row16 * 4 + 3] + q2[0];
            }
        }
    } else if constexpr (EPI == EPR_HZ) {
        float* ep = (float*)Bsm;   // [16][256] f32, reuses Bsm after final sync
        const float D0 = q0[0];
        const int y = blockIdx.y;
        if (wave >= 2) {
            #pragma unroll
            for (int c = 0; c < NF; ++c) {
                const int lc = (wave * NF + c) * 16 + l16;          // 256..512
                const float bz = bias[512 + y * 256 + lc - 256];
                #pragma unroll
                for (int r = 0; r < 4; ++r) {
                    const float z = acc[c][r] + bz;
                    ep[(quad * 4 + r) * 256 + lc - 256] = z / (1.f + __expf(-z)) + D0;
                }
            }
        }
        __syncthreads();
        if (wave < 2) {
            #pragma unroll
            for (int c = 0; c < NF; ++c) {
                const int lc = (wave * NF + c) * 16 + l16;          // 0..256
                const float bh = bias[y * 256 + lc];
                #pragma unroll
                for (int r = 0; r < 4; ++r) {
                    const float v = (acc[c][r] + bh) * ep[(quad * 4 + r) * 256 + lc];
                    outb[(size_t)(m0 + quad * 4 + r) * 512 + y * 256 + lc] = f2b(v);
                }
            }
        }
    } else {  // EPR_FINAL
        float fv[4][4], s[4], q[4];
        #pragma unroll
        for (int r = 0; r < 4; ++r) { s[r] = 0.f; q[r] = 0.f; }
        #pragma unroll
        for (int c = 0; c < NF; ++c) {
            const int col = (wave * NF + c) * 16 + l16;
            #pragma unroll
            for (int r = 0; r < 4; ++r) {
                const size_t idx = (size_t)(m0 + quad * 4 + r) * 256 + col;
                const float g = 1.f / (1.f + __expf(-acc[c][r]));
                const float f = g * q0[idx] + (1.f - g) * q1[idx] + q2[idx];
                fv[c][r] = f; s[r] += f; q[r] += f * f;
            }
        }
        #pragma unroll
        for (int r = 0; r < 4; ++r) {
            #pragma unroll
            for (int o = 1; o < 16; o <<= 1) { s[r] += __shfl_xor(s[r], o); q[r] += __shfl_xor(q[r], o); }
        }
        if (l16 == 0) {
            #pragma unroll
            for (int r = 0; r < 4; ++r) {
                red[(quad * 4 + r) * 8 + wave * 2]     = s[r];
                red[(quad * 4 + r) * 8 + wave * 2 + 1] = q[r];
            }
        }
        __syncthreads();
        #pragma unroll
        for (int r = 0; r < 4; ++r) {
            const int row16 = quad * 4 + r;
            float S = 0.f, Q = 0.f;
            #pragma unroll
            for (int w = 0; w < 4; ++w) { S += red[row16 * 8 + w * 2]; Q += red[row16 * 8 + w * 2 + 1]; }
            const float mean = S * (1.f / 256.f);
            const float rstd = rsqrtf(Q * (1.f / 256.f) - mean * mean + 1e-5f);
            #pragma unroll
            for (int c = 0; c < NF; ++c) {
                const int col = (wave * NF + c) * 16 + l16;
                outf[(size_t)(m0 + row16) * 256 + col] = (fv[c][r] - mean) * rstd * q3[col] + q4[col];
            }
        }
    }
}

// ---------------------------------------------------------------------------
// Fused GAT attention (round-4 structure, unchanged): LDS-staged, 64 i-rows,
// 4-way j-split partials.
// ---------------------------------------------------------------------------
__global__ __launch_bounds__(256) void attn_kernel(
    const int* __restrict__ adj, const float* __restrict__ sA,
    const float* __restrict__ dA, const ushort* __restrict__ WhT,
    float* __restrict__ Upart, float* __restrict__ lpart)
{
    __shared__ ushort vsm[256 * 64];
    __shared__ ushort wsm[64 * 64];

    const int tid  = threadIdx.x;
    const int wave = tid >> 6, lane = tid & 63, quad = lane >> 4, l16 = lane & 15;
    const int lr = lane >> 3, ls = lane & 7;
    const int i0 = blockIdx.x * 64;
    const int js = blockIdx.y;
    const int jbase = js * 2048;
    const int pr = tid >> 2, pc = tid & 3;
    const float s_r = sA[i0 + pr];
    const int* adjp = adj + (size_t)(i0 + pr) * 8192 + jbase;
    const int rt = wave & 1, ch = wave >> 1;

    f32x4 zero = {0.f, 0.f, 0.f, 0.f};
    f32x4 acc[2][8] = {{zero, zero, zero, zero, zero, zero, zero, zero},
                       {zero, zero, zero, zero, zero, zero, zero, zero}};
    float lsum = 0.f;

    for (int c64 = 0; c64 < 2048; c64 += 64) {
        #pragma unroll
        for (int p = 0; p < 8; ++p) {
            const int f = wave * 64 + p * 8 + lr;
            load_lds_16(WhT + (size_t)f * 8192 + jbase + c64 + ((ls ^ (f & 7)) * 8),
                        vsm + (size_t)(wave * 64 + p * 8) * 64);
        }
        #pragma unroll
        for (int gi = 0; gi < 2; ++gi) {
            const int g = pc + gi * 4;
            const int4   a0 = *(const int4*)  (adjp + c64 + g * 8);
            const int4   a1 = *(const int4*)  (adjp + c64 + g * 8 + 4);
            const float4 d0 = *(const float4*)(dA + jbase + c64 + g * 8);
            const float4 d1 = *(const float4*)(dA + jbase + c64 + g * 8 + 4);
            const int   aa[8] = {a0.x, a0.y, a0.z, a0.w, a1.x, a1.y, a1.z, a1.w};
            const float dd[8] = {d0.x, d0.y, d0.z, d0.w, d1.x, d1.y, d1.z, d1.w};
            union { ushort us[8]; uint4 v; } pk;
            #pragma unroll
            for (int q = 0; q < 8; ++q) {
                float e = s_r + dd[q];
                e = fmaxf(e, 0.2f * e);
                const float w = aa[q] ? __expf(e) : 0.f;
                lsum += w; pk.us[q] = f2b(w);
            }
            *(uint4*)(wsm + pr * 64 + ((g ^ (pr & 7)) * 8)) = pk.v;
        }
        __syncthreads();

        #pragma unroll
        for (int ks = 0; ks < 2; ++ks) {
            const int sl = ((ks * 4 + quad) ^ (l16 & 7)) * 8;
            short8 a0 = *(const short8*)(wsm + (rt * 32 + l16) * 64 + sl);
            short8 a1 = *(const short8*)(wsm + (rt * 32 + 16 + l16) * 64 + sl);
            #pragma unroll
            for (int c = 0; c < 8; ++c) {
                short8 bf = *(const short8*)(vsm + (ch * 128 + c * 16 + l16) * 64 + sl);
                acc[0][c] = __builtin_amdgcn_mfma_f32_16x16x32_bf16(a0, bf, acc[0][c], 0, 0, 0);
                acc[1][c] = __builtin_amdgcn_mfma_f32_16x16x32_bf16(a1, bf, acc[1][c], 0, 0, 0);
            }
        }
        __syncthreads();
    }

    lsum += __shfl_down(lsum, 1);
    lsum += __shfl_down(lsum, 2);
    if (pc == 0) lpart[(size_t)js * 8192 + i0 + pr] = lsum;

    #pragma unroll
    for (int it = 0; it < 2; ++it) {
        #pragma unroll
        for (int c = 0; c < 8; ++c) {
            const int col = ch * 128 + c * 16 + l16;
            #pragma unroll
            for (int r = 0; r < 4; ++r) {
                const int row = i0 + rt * 32 + it * 16 + quad * 4 + r;
                Upart[((size_t)js * 8192 + row) * 256 + col] = acc[it][c][r];
            }
        }
    }
}

__global__ __launch_bounds__(256) void attn_combine_kernel(
    const float* __restrict__ Upart, const float* __restrict__ lpart,
    float* __restrict__ outf, ushort* __restrict__ outb)
{
    const int row = blockIdx.x * 4 + (threadIdx.x >> 6);
    const int lane = threadIdx.x & 63;
    float l = 0.f;
    #pragma unroll
    for (int js = 0; js < 4; ++js) l += lpart[(size_t)js * 8192 + row];
    const float inv = 1.f / l;
    #pragma unroll
    for (int i = 0; i < 4; ++i) {
        const int c = i * 64 + lane;
        float u = 0.f;
        #pragma unroll
        for (int js = 0; js < 4; ++js)
            u += Upart[((size_t)js * 8192 + row) * 256 + c];
        const float v = u * inv;
        outf[(size_t)row * 256 + c] = v;
        outb[(size_t)row * 512 + c] = f2b(v);
    }
}

// ---------------------------------------------------------------------------
// Descriptor-driven transpose/cast mega-kernel. perm=1 applies the hz column
// permutation so (h_c, z_c) land in the same 512-row half of hzT.
// ---------------------------------------------------------------------------
struct TJob { const float* in; ushort* out; int R, C, off, perm; };
struct TArgs { TJob j[10]; };

DEVINL int hzperm(int j) {
    return (j < 512) ? ((j >> 8) << 9) + (j & 255)
                     : (((j - 512) >> 8) << 9) + 256 + ((j - 512) & 255);
}

__global__ __launch_bounds__(256) void multi_transpose_kernel(TArgs a)
{
    __shared__ float tile[32][33];
    const int b = blockIdx.x;
    int ji = 0;
    #pragma unroll
    for (int k = 1; k < 10; ++k) if (b >= a.j[k].off) ji = k;
    const TJob J = a.j[ji];
    const int t = b - J.off;

    if (J.R == 0) {            // flat cast
        const int base = t * 1024 + threadIdx.x;
        #pragma unroll
        for (int k = 0; k < 4; ++k)
            J.out[base + k * 256] = f2b(J.in[base + k * 256]);
        return;
    }
    const int CB = J.C >> 5;
    const int bx = t % CB, by = t / CB;
    const int tx = threadIdx.x & 31, ty = threadIdx.x >> 5;
    const int c0 = bx * 32, r0 = by * 32;
    #pragma unroll
    for (int i = ty; i < 32; i += 8)
        tile[i][tx] = J.in[(size_t)(r0 + i) * J.C + (c0 + tx)];
    __syncthreads();
    #pragma unroll
    for (int i = ty; i < 32; i += 8) {
        int orow = c0 + i;
        if (J.perm) orow = hzperm(orow);
        J.out[(size_t)orow * J.R + (r0 + tx)] = f2b(tile[tx][i]);
    }
}

// f32 [R][C] -> bf16 [C][R]  (Wh -> WhT, mid-pipeline)
__global__ __launch_bounds__(256) void transpose_cast_kernel(
    const float* __restrict__ in, ushort* __restrict__ out, int R, int C)
{
    __shared__ float tile[32][33];
    const int tx = threadIdx.x & 31, ty = threadIdx.x >> 5;
    const int c0 = blockIdx.x * 32, r0 = blockIdx.y * 32;
    #pragma unroll
    for (int i = ty; i < 32; i += 8)
        tile[i][tx] = in[(size_t)(r0 + i) * C + (c0 + tx)];
    __syncthreads();
    #pragma unroll
    for (int i = ty; i < 32; i += 8)
        out[(size_t)(c0 + i) * R + (r0 + tx)] = f2b(tile[tx][i]);
}

// ---------------------------------------------------------------------------
extern "C" void kernel_launch(void* const* d_in, const int* in_sizes, int n_in,
                              void* d_out, int out_size, void* d_ws, size_t ws_size,
                              hipStream_t stream)
{
    const float* h      = (const float*)d_in[0];
    const int*   adj    = (const int*)  d_in[1];
    const float* W      = (const float*)d_in[2];
    const float* a_src  = (const float*)d_in[3];
    const float* a_dst  = (const float*)d_in[4];
    const float* W_bcdt = (const float*)d_in[5];
    const float* b_bcdt = (const float*)d_in[6];
    const float* abp_w  = (const float*)d_in[7];
    const float* abp_b  = (const float*)d_in[8];
    const float* cp_w   = (const float*)d_in[9];
    const float* cp_b   = (const float*)d_in[10];
    const float* W_hz   = (const float*)d_in[11];
    const float* b_hz   = (const float*)d_in[12];
    const float* out_w  = (const float*)d_in[13];
    const float* out_b  = (const float*)d_in[14];
    const float* fe1_w  = (const float*)d_in[15];
    const float* fe1_b  = (const float*)d_in[16];
    const float* fe_ln_g= (const float*)d_in[17];
    const float* fe_ln_b= (const float*)d_in[18];
    const float* fe2_w  = (const float*)d_in[19];
    const float* fe2_b  = (const float*)d_in[20];
    const float* Avec   = (const float*)d_in[21];
    const float* Dvec   = (const float*)d_in[22];
    const float* g1_w   = (const float*)d_in[23];
    const float* g1_b   = (const float*)d_in[24];
    const float* g_ln_g = (const float*)d_in[25];
    const float* g_ln_b = (const float*)d_in[26];
    const float* g2_w   = (const float*)d_in[27];
    const float* g2_b   = (const float*)d_in[28];
    const float* ln_g   = (const float*)d_in[29];
    const float* ln_b   = (const float*)d_in[30];
    float* outp = (float*)d_out;

    char* p = (char*)d_ws;
    size_t off = 0;
    auto take = [&](size_t nbytes) -> void* {
        void* r = p + off;
        off += (nbytes + 255) & ~(size_t)255;
        return r;
    };
    ushort* wT    = (ushort*)take(256 * 256 * 2);
    ushort* fe1T  = (ushort*)take(512 * 256 * 2);
    ushort* fe2T  = (ushort*)take(256 * 512 * 2);
    ushort* bcdtT = (ushort*)take(384 * 256 * 2);
    ushort* hzT   = (ushort*)take(1024 * 256 * 2);
    ushort* outT  = (ushort*)take(256 * 512 * 2);
    ushort* g1T   = (ushort*)take(512 * 512 * 2);
    ushort* g2T   = (ushort*)take(256 * 512 * 2);
    ushort* abpT  = (ushort*)take(256 * 128 * 2);
    ushort* hbf   = (ushort*)take((size_t)8192 * 256 * 2);
    float*  Wh    = (float*) take((size_t)8192 * 256 * 4);
    ushort* Whbf  = (ushort*)take((size_t)8192 * 256 * 2);
    ushort* WhT   = (ushort*)take((size_t)8192 * 256 * 2);
    float*  sbuf  = (float*) take(8192 * 4);
    float*  dbuf  = (float*) take(8192 * 4);
    float*  cscl  = (float*) take(8192 * 4);
    float*  hattn = (float*) take((size_t)8192 * 256 * 4);
    float*  henh  = (float*) take((size_t)8192 * 256 * 4);
    float*  lpart = (float*) take(4 * 8192 * 4);
    ushort* SB    = (ushort*)take((size_t)8192 * 128 * 2);
    ushort* hsbf  = (ushort*)take((size_t)8192 * 256 * 2);
    ushort* vbf   = (ushort*)take((size_t)8192 * 512 * 2);
    float*  hs2   = (float*) take((size_t)8192 * 256 * 4);
    ushort* comb  = (ushort*)take((size_t)8192 * 512 * 2);
    ushort* tact  = (ushort*)take((size_t)8192 * 512 * 2);
    float*  Upart = (float*) take((size_t)4 * 8192 * 256 * 4);

    (void)in_sizes; (void)n_in; (void)out_size; (void)ws_size;

    // zero the atomic accumulators for the fused s/d row-dots
    hipMemsetAsync(sbuf, 0, 2 * 8192 * sizeof(float), stream);

    // ALL weight transposes + h cast in one dispatch
    {
        TArgs ta; int boff = 0;
        auto addT = [&](int i, const float* in, ushort* out, int R, int C, int perm) {
            ta.j[i] = TJob{in, out, R, C, boff, perm};
            boff += (R / 32) * (C / 32);
        };
        addT(0, W,      wT,    256, 256,  0);
        addT(1, fe1_w,  fe1T,  256, 512,  0);
        addT(2, fe2_w,  fe2T,  512, 256,  0);
        addT(3, W_bcdt, bcdtT, 256, 384,  0);
        addT(4, abp_w,  abpT,  128, 256,  0);
        addT(5, W_hz,   hzT,   256, 1024, 1);   // permuted (h,z pairing)
        addT(6, out_w,  outT,  512, 256,  0);
        addT(7, g1_w,   g1T,   512, 512,  0);
        addT(8, g2_w,   g2T,   512, 256,  0);
        ta.j[9] = TJob{h, hbf, 0, 8192 * 256, boff, 0};   // flat cast
        boff += (8192 * 256) / 1024;
        multi_transpose_kernel<<<boff, 256, 0, stream>>>(ta);
    }

    // Wh = h @ W  (f32 + bf16) with fused s/d row-dot atomics
    gemm_k<256, EPI_WH><<<dim3(128, 4), 256, 0, stream>>>(
        hbf, wT, nullptr, 256, Wh, Whbf, 256, 0, nullptr, a_src, a_dst, sbuf, dbuf);
    transpose_cast_kernel<<<dim3(8, 256), 256, 0, stream>>>(Wh, WhT, 8192, 256);

    // fused GAT attention
    attn_kernel<<<dim3(128, 4), 256, 0, stream>>>(adj, sbuf, dbuf, WhT, Upart, lpart);
    attn_combine_kernel<<<2048, 256, 0, stream>>>(Upart, lpart, hattn, comb);

    // feature enhancer: fe1+LN+silu fused, then fe2
    gemm_row<256, 512, EPR_LNSILU><<<512, 256, 0, stream>>>(
        Whbf, fe1T, fe1_b, nullptr, tact, fe_ln_g, fe_ln_b, nullptr, nullptr, nullptr);
    gemm_k<512, EPI_F32><<<dim3(128, 4), 256, 0, stream>>>(
        tact, fe2T, fe2_b, 256, henh, nullptr, 0, 0, nullptr, nullptr, nullptr, nullptr, nullptr);

    // SSM branch: bcdt+softmax+cscale fused; SB gemm; hz+act fused; out gemm
    gemm_row<256, 384, EPR_BCDT><<<512, 256, 0, stream>>>(
        Whbf, bcdtT, b_bcdt, cscl, SB, Avec, cp_w, cp_b, nullptr, nullptr);
    gemm_k<128, EPI_MUL_BF16><<<dim3(128, 4), 256, 0, stream>>>(
        SB, abpT, abp_b, 256, nullptr, hsbf, 256, 0, Wh, nullptr, nullptr, nullptr, nullptr);
    gemm_row<256, 512, EPR_HZ><<<dim3(512, 2), 256, 0, stream>>>(
        hsbf, hzT, b_hz, nullptr, vbf, Dvec, nullptr, nullptr, nullptr, nullptr);
    gemm_k<512, EPI_SCALE_FB><<<dim3(128, 4), 256, 0, stream>>>(
        vbf, outT, out_b, 256, hs2, comb, 512, 256, cscl, nullptr, nullptr, nullptr, nullptr);

    // gated fusion: g1+LN+silu fused, then g2+sigmoid+fuse+final-LN fused
    gemm_row<512, 512, EPR_LNSILU><<<512, 256, 0, stream>>>(
        comb, g1T, g1_b, nullptr, tact, g_ln_g, g_ln_b, nullptr, nullptr, nullptr);
    gemm_row<512, 256, EPR_FINAL><<<512, 256, 0, stream>>>(
        tact, g2T, g2_b, outp, nullptr, hattn, hs2, henh, ln_g, ln_b);
}